// Round 7
// baseline (55.416 us; speedup 1.0000x reference)
//
#include <hip/hip_runtime.h>
#include <hip/hip_bf16.h>

#define NBATCH 4
#define NNODE  20000
#define NF     128
#define NK     16
#define NROWS  (NBATCH * NNODE)   // 80000
#define NBLK   1250               // 64 rows per block
#define WTF_BYTES 65536           // 16c x 4s x 64lane x 16B fragment-permuted weights
#define BIAS_OFF  WTF_BYTES
#define S_OFF     (WTF_BYTES + 1024)          // bf16 s = x*Ws + b   (20.48 MB)
#define Y_OFF     (S_OFF + NROWS * NF * 2)    // fp8  y = x*Wn       (10.24 MB)

typedef __attribute__((ext_vector_type(8))) short bf16x8_t;
typedef __attribute__((ext_vector_type(4))) float f32x4_t;
typedef __attribute__((ext_vector_type(2))) float f32x2_t;

__device__ __forceinline__ unsigned int f2bf(float f) {
  unsigned int u = __float_as_uint(f);
  u += 0x7fffu + ((u >> 16) & 1u);
  return u >> 16;
}

__device__ __forceinline__ int xcd_swz(int orig) {
  // bijective XCD-chunked swizzle for nwg=1250: q=156, r=2
  const int xcd = orig & 7, i = orig >> 3;
  const int q = NBLK / 8, r = NBLK % 8;
  return (xcd < r ? xcd * (q + 1) : r * (q + 1) + (xcd - r) * q) + i;
}

// ---------------- K1: weight fragments + bias sum ------------------------
__global__ __launch_bounds__(256) void sage_wprep(
    const float* __restrict__ Ws, const float* __restrict__ bs,
    const float* __restrict__ Wn, const float* __restrict__ bn,
    unsigned char* __restrict__ ws)
{
  const int bid = blockIdx.x, tid = threadIdx.x;
  if (bid == 16) {
    if (tid < NF) ((float*)(ws + BIAS_OFF))[tid] = bs[tid] + bn[tid];
    return;
  }
  const int ft = bid * 256 + tid;       // 0..4095
  const int gc = ft >> 8;               // col tile 0..15
  const int s  = (ft >> 6) & 3;         // k-step 0..3
  const int l  = ft & 63;
  const int colg = gc * 16 + (l & 15);  // 0..255 (stacked N)
  const int k0 = s * 32 + ((l >> 4) << 3);
  const float* W = (colg < NF) ? Ws : Wn;
  const int col = (colg < NF) ? colg : colg - NF;
  unsigned int w[4];
#pragma unroll
  for (int jj = 0; jj < 4; ++jj) {
    const float va = W[(k0 + 2 * jj) * NF + col];
    const float vb = W[(k0 + 2 * jj + 1) * NF + col];
    w[jj] = f2bf(va) | (f2bf(vb) << 16);
  }
  *reinterpret_cast<uint4*>(ws + (size_t)ft * 16) = make_uint4(w[0], w[1], w[2], w[3]);
}

// ---------------- K2: dense GEMM  s = x*Ws + b (bf16), y = x*Wn (fp8) ----
__global__ __launch_bounds__(256) void sage_gemm(
    const float* __restrict__ x, unsigned char* __restrict__ ws)
{
  const int tid = threadIdx.x, lane = tid & 63, wid = tid >> 6;
  const int bid = xcd_swz(blockIdx.x);
  const int row0 = bid * 64 + wid * 16;
  const int fl = lane & 15, q = lane >> 4;

  // A fragments: 16 rows x K=128, straight from f32 x, inline bf16 convert
  bf16x8_t afr[4];
  const float* xr = x + (size_t)(row0 + fl) * NF + q * 8;
#pragma unroll
  for (int s = 0; s < 4; ++s) {
    const float4 v0 = *reinterpret_cast<const float4*>(xr + s * 32);
    const float4 v1 = *reinterpret_cast<const float4*>(xr + s * 32 + 4);
    union { unsigned int u[4]; bf16x8_t v; } r;
    r.u[0] = f2bf(v0.x) | (f2bf(v0.y) << 16);
    r.u[1] = f2bf(v0.z) | (f2bf(v0.w) << 16);
    r.u[2] = f2bf(v1.x) | (f2bf(v1.y) << 16);
    r.u[3] = f2bf(v1.z) | (f2bf(v1.w) << 16);
    afr[s] = r.v;
  }

  f32x4_t acc[16];
#pragma unroll
  for (int c = 0; c < 16; ++c) acc[c] = (f32x4_t){0.f, 0.f, 0.f, 0.f};

  const bf16x8_t* wtf = reinterpret_cast<const bf16x8_t*>(ws);
#pragma unroll
  for (int c = 0; c < 16; ++c) {
#pragma unroll
    for (int s = 0; s < 4; ++s) {
      acc[c] = __builtin_amdgcn_mfma_f32_16x16x32_bf16(
          afr[s], wtf[(c * 4 + s) * 64 + lane], acc[c], 0, 0, 0);
    }
  }

  const float* bias = reinterpret_cast<const float*>(ws + BIAS_OFF);
  unsigned short* sp = reinterpret_cast<unsigned short*>(ws + S_OFF);
  unsigned char*  yp = ws + Y_OFF;

  // s-half: cols 0..127 (x*Ws), + (b_self+b_nei), bf16
#pragma unroll
  for (int c = 0; c < 8; ++c) {
    const int col = c * 16 + fl;
    const float b = bias[col];
#pragma unroll
    for (int j = 0; j < 4; ++j) {
      const int r = row0 + q * 4 + j;
      sp[(size_t)r * NF + col] = (unsigned short)f2bf(acc[c][j] + b);
    }
  }
  // y-half: cols 128..255 (x*Wn), fp8 e4m3
#pragma unroll
  for (int c = 8; c < 16; ++c) {
    const int col = (c - 8) * 16 + fl;
#pragma unroll
    for (int j = 0; j < 4; ++j) {
      const int r = row0 + q * 4 + j;
      const int p8 = __builtin_amdgcn_cvt_pk_fp8_f32(acc[c][j], acc[c][j], 0, false);
      yp[(size_t)r * NF + col] = (unsigned char)(p8 & 0xff);
    }
  }
}

// ---------------- K3: out = relu(s + mean_k y[idx_k]) --------------------
__global__ __launch_bounds__(256) void sage_finish(
    const unsigned char* __restrict__ ws, const int* __restrict__ adj,
    float* __restrict__ out)
{
  const int tid = threadIdx.x, lane = tid & 63, wid = tid >> 6;
  const int bid = xcd_swz(blockIdx.x);
  const int rg = lane >> 4, fl = lane & 15;   // 4 rows/wave, 16 lanes/row

  const unsigned short* sp = reinterpret_cast<const unsigned short*>(ws + S_OFF);
  const unsigned char*  yp = ws + Y_OFF;

#pragma unroll
  for (int it = 0; it < 4; ++it) {
    const int row = bid * 64 + wid * 16 + it * 4 + rg;
    const int b = row / NNODE;
    const unsigned char* yb = yp + (size_t)b * NNODE * NF + fl * 8;
    const int4* a4 = reinterpret_cast<const int4*>(adj + (size_t)row * NK);
    const int4 t0 = a4[0], t1 = a4[1], t2 = a4[2], t3 = a4[3];
    const int idx[16] = {t0.x, t0.y, t0.z, t0.w, t1.x, t1.y, t1.z, t1.w,
                         t2.x, t2.y, t2.z, t2.w, t3.x, t3.y, t3.z, t3.w};

    const uint4 sv = *reinterpret_cast<const uint4*>(sp + (size_t)row * NF + fl * 8);

    float a[8];
#pragma unroll
    for (int e = 0; e < 8; ++e) a[e] = 0.f;

#define ACC2(word, base)                                                   \
    {                                                                      \
      f32x2_t lo = __builtin_amdgcn_cvt_pk_f32_fp8((word), false);         \
      f32x2_t hi = __builtin_amdgcn_cvt_pk_f32_fp8((word), true);          \
      a[(base) + 0] += lo[0]; a[(base) + 1] += lo[1];                      \
      a[(base) + 2] += hi[0]; a[(base) + 3] += hi[1];                      \
    }
#pragma unroll
    for (int g = 0; g < 4; ++g) {
      uint2 v0 = *reinterpret_cast<const uint2*>(yb + (size_t)idx[g * 4 + 0] * NF);
      uint2 v1 = *reinterpret_cast<const uint2*>(yb + (size_t)idx[g * 4 + 1] * NF);
      uint2 v2 = *reinterpret_cast<const uint2*>(yb + (size_t)idx[g * 4 + 2] * NF);
      uint2 v3 = *reinterpret_cast<const uint2*>(yb + (size_t)idx[g * 4 + 3] * NF);
      ACC2(v0.x, 0) ACC2(v0.y, 4)
      ACC2(v1.x, 0) ACC2(v1.y, 4)
      ACC2(v2.x, 0) ACC2(v2.y, 4)
      ACC2(v3.x, 0) ACC2(v3.y, 4)
    }
#undef ACC2

    float se[8];
    se[0] = __uint_as_float(sv.x << 16); se[1] = __uint_as_float(sv.x & 0xffff0000u);
    se[2] = __uint_as_float(sv.y << 16); se[3] = __uint_as_float(sv.y & 0xffff0000u);
    se[4] = __uint_as_float(sv.z << 16); se[5] = __uint_as_float(sv.z & 0xffff0000u);
    se[6] = __uint_as_float(sv.w << 16); se[7] = __uint_as_float(sv.w & 0xffff0000u);

    const float sc = 1.f / 16.f;
    float4 o0, o1;
    o0.x = fmaxf(se[0] + a[0] * sc, 0.f);
    o0.y = fmaxf(se[1] + a[1] * sc, 0.f);
    o0.z = fmaxf(se[2] + a[2] * sc, 0.f);
    o0.w = fmaxf(se[3] + a[3] * sc, 0.f);
    o1.x = fmaxf(se[4] + a[4] * sc, 0.f);
    o1.y = fmaxf(se[5] + a[5] * sc, 0.f);
    o1.z = fmaxf(se[6] + a[6] * sc, 0.f);
    o1.w = fmaxf(se[7] + a[7] * sc, 0.f);
    float* op = out + (size_t)row * NF + fl * 8;
    *reinterpret_cast<float4*>(op)     = o0;
    *reinterpret_cast<float4*>(op + 4) = o1;
  }
}

extern "C" void kernel_launch(void* const* d_in, const int* in_sizes, int n_in,
                              void* d_out, int out_size, void* d_ws, size_t ws_size,
                              hipStream_t stream) {
  const float* x     = (const float*)d_in[0];
  const int*   adj   = (const int*)d_in[1];
  const float* Wself = (const float*)d_in[2];
  const float* bself = (const float*)d_in[3];
  const float* Wnei  = (const float*)d_in[4];
  const float* bnei  = (const float*)d_in[5];
  float* out = (float*)d_out;
  unsigned char* ws = (unsigned char*)d_ws;

  hipLaunchKernelGGL(sage_wprep, dim3(17), dim3(256), 0, stream,
                     Wself, bself, Wnei, bnei, ws);
  hipLaunchKernelGGL(sage_gemm, dim3(NBLK), dim3(256), 0, stream, x, ws);
  hipLaunchKernelGGL(sage_finish, dim3(NBLK), dim3(256), 0, stream,
                     ws, adj, out);
}